// Round 14
// baseline (1649.191 us; speedup 1.0000x reference)
//
#include <hip/hip_runtime.h>
#include <math.h>

typedef unsigned short u16;
typedef short s16x8 __attribute__((ext_vector_type(8)));
typedef float f32x4 __attribute__((ext_vector_type(4)));

#define NITER 32   // K=1024 / BK=32 k-tiles
#define ARW 72     // u16 per A LDS row (small-level kernel only)

// Pre-split, transposed weights: layout [kb 32][gate 5][j 512][k 32]
__device__ __align__(16) u16 g_Bhi[1024 * 2560];
__device__ __align__(16) u16 g_Blo[1024 * 2560];
// Pre-split leaf A panel: row i -> split emb[tokens[i]] (1024 u16 = 32 chunks of [16hi|16lo])
__device__ __align__(16) u16 g_Aleaf[(size_t)64 * 1024 * 1024];

__device__ __forceinline__ u16 f2bf(float x) {
    unsigned u = __float_as_uint(x);
    u += 0x7fffu + ((u >> 16) & 1u);       // RNE
    return (u16)(u >> 16);
}
__device__ __forceinline__ float bf2f(u16 h) { return __uint_as_float(((unsigned)h) << 16); }
__device__ __forceinline__ float sigm(float x) { return 1.0f / (1.0f + expf(-x)); }
__device__ __forceinline__ unsigned pk(u16 a, u16 b) { return (unsigned)a | ((unsigned)b << 16); }

__device__ __forceinline__ void gload16(const void* g, u16* l) {
    __builtin_amdgcn_global_load_lds(
        (const __attribute__((address_space(1))) void*)g,
        (__attribute__((address_space(3))) void*)(void*)l, 16, 0, 0);
}

// ---------------- weight split+transpose: W[k][col] f32 -> [kb][g][j][k] bf16 hi/lo ----------
__global__ __launch_bounds__(256)
void wsplit_kernel(const float* __restrict__ Wiou, const float* __restrict__ Wf)
{
    __shared__ float tile[32][65];
    const int kb = blockIdx.x;           // 0..31
    const int cb = blockIdx.y;           // 0..39
    const int t  = threadIdx.x;
    const int c0 = cb * 64;

    {
        const int kk  = t >> 3;
        const int cu0 = (t & 7) * 8;
        const int k   = kb * 32 + kk;
#pragma unroll
        for (int u = 0; u < 8; u++) {
            int c = c0 + cu0 + u;
            float v = (c < 1536) ? Wiou[(size_t)k * 1536 + c]
                                 : Wf[(size_t)k * 1024 + (c - 1536)];
            tile[kk][cu0 + u] = v;
        }
    }
    __syncthreads();
    {
        const int jl = t >> 2;
        const int kc = (t & 3) * 8;
        const int g  = c0 >> 9;
        const int j  = (c0 & 511) + jl;
        size_t dst = (((size_t)kb * 5 + g) * 512 + j) * 32 + kc;
        unsigned ph[4], pl[4];
#pragma unroll
        for (int u = 0; u < 4; u++) {
            float v0 = tile[kc + 2 * u][jl];
            float v1 = tile[kc + 2 * u + 1][jl];
            u16 h0 = f2bf(v0), h1 = f2bf(v1);
            u16 l0 = f2bf(v0 - bf2f(h0)), l1 = f2bf(v1 - bf2f(h1));
            ph[u] = pk(h0, h1);
            pl[u] = pk(l0, l1);
        }
        *(uint4*)(g_Bhi + dst) = make_uint4(ph[0], ph[1], ph[2], ph[3]);
        *(uint4*)(g_Blo + dst) = make_uint4(pl[0], pl[1], pl[2], pl[3]);
    }
}

// ---------------- leaf A gather+split ----------------
__global__ __launch_bounds__(256)
void leafgather_kernel(const int* __restrict__ tokens, const float* __restrict__ emb)
{
    const int gidx = blockIdx.x * 256 + threadIdx.x;   // chunk id
    const int row  = gidx >> 5;
    const int c    = gidx & 31;
    const int tok  = tokens[row];
    const float* src = emb + (size_t)tok * 512 + c * 16;
    u16* dst = g_Aleaf + (size_t)row * 1024 + c * 32;

    float4 f0 = *(const float4*)(src);
    float4 f1 = *(const float4*)(src + 4);
    float4 f2 = *(const float4*)(src + 8);
    float4 f3 = *(const float4*)(src + 12);
    float v[16] = {f0.x,f0.y,f0.z,f0.w, f1.x,f1.y,f1.z,f1.w,
                   f2.x,f2.y,f2.z,f2.w, f3.x,f3.y,f3.z,f3.w};
    unsigned ph[8], pl[8];
#pragma unroll
    for (int i = 0; i < 8; i++) {
        u16 h0 = f2bf(v[2*i]),   h1 = f2bf(v[2*i+1]);
        u16 l0 = f2bf(v[2*i]   - bf2f(h0));
        u16 l1 = f2bf(v[2*i+1] - bf2f(h1));
        ph[i] = pk(h0, h1);
        pl[i] = pk(l0, l1);
    }
    *(uint4*)(dst)      = make_uint4(ph[0], ph[1], ph[2], ph[3]);
    *(uint4*)(dst + 8)  = make_uint4(ph[4], ph[5], ph[6], ph[7]);
    *(uint4*)(dst + 16) = make_uint4(pl[0], pl[1], pl[2], pl[3]);
    *(uint4*)(dst + 24) = make_uint4(pl[4], pl[5], pl[6], pl[7]);
}

// ---------------- big levels (np>=64): BK=64 windows + register pipelining ----------------
// R13 structure with two dependency gaps closed:
//  - DUAL B register sets (next-tile B issued a full tile (~290cy) before use >= L2 latency)
//  - A-frag prefetch: T1 hi-frags (ahn) read under T0 pass3; T1 lo-frags reuse dead al regs;
//    window-crossing frags read right after the barrier (one exposed lgkm per 2 tiles).
// vmcnt(10) at the window barrier waits exactly the 4 oldest (the A gload_lds) per m135.
template<bool LEAF>
__global__ __launch_bounds__(256, 2)
void level_big(const u16* __restrict__ Hcin, const float* __restrict__ Cc,
               const float* __restrict__ b_iou, const float* __restrict__ b_f,
               u16* __restrict__ Hp, float* __restrict__ Cp,
               int np, int lgnp)
{
    __shared__ __align__(16) u16 Ab0[8192];   // 16 KB: k-tiles {t0, t0+1}
    __shared__ __align__(16) u16 Ab1[8192];   // 16 KB: next window

    const u16* Hc = LEAF ? g_Aleaf : Hcin;

    const int tid = threadIdx.x;
    const int jg  = blockIdx.x;          // 0..7 -> XCD pinning via %8
    const int m0  = blockIdx.y * 64;
    const int j0  = jg * 64;
    const int nc  = np * 2;

    const int w    = tid >> 6;
    const int lane = tid & 63;
    const int il   = lane & 15;
    const int kq   = lane >> 4;
    const int wc   = w;                  // j sub-range wc*16 .. +15

    f32x4 acc[4][5];
#pragma unroll
    for (int rf = 0; rf < 4; rf++)
#pragma unroll
        for (int g = 0; g < 5; g++) acc[rf][g] = (f32x4)0.0f;

    // ---- A staging: uniform base + constant per-lane offset (swizzled source) ----
    const int bA  = m0 >> lgnp;
    const int pA0 = m0 & (np - 1);
    const char* A0u = (const char*)(Hc + ((size_t)bA * nc + 2 * pA0) * 1024);  // uniform
    const int rowS = tid >> 3;                       // A-row 0..31 (instr0), +32 (instr1)
    const int segS = (tid & 7) ^ (rowS & 7);         // swizzled source slot
    const unsigned voffA = (unsigned)rowS * 4096u + (unsigned)segS * 16u;      // bytes, const

    // ---- A read offsets (swizzled, per-thread constants) ----
    const int shi = ((kq >> 1) << 2) | (kq & 1);     // hi slot for this kq
    const int x7  = il & 7;
    const int aoh = il * 64 + ((shi ^ x7) * 8);
    const int aol = il * 64 + (((shi + 2) ^ x7) * 8);

    // ---- B: uniform bases + 5 constant per-thread offsets ----
    const char* BH0 = (const char*)(g_Bhi + (size_t)j0 * 32);   // uniform
    const char* BL0 = (const char*)(g_Blo + (size_t)j0 * 32);   // uniform
    unsigned vB[5];
#pragma unroll
    for (int g = 0; g < 5; g++)
        vB[g] = (unsigned)(((wc * 16 + il) * 32 + kq * 8) * 2 + g * 32768);

    // B dual register sets; A frags: ah/al (current), ahn (next-tile hi; lo reuses al)
    s16x8 b0h[5], b0l[5], b1h[5], b1l[5];
    s16x8 ah[4], al[4], ahn[4];

#define STAGEA2(DST, t_)                                                       \
    {                                                                          \
        const char* ab = A0u + (size_t)(t_) * 128;                             \
        gload16(ab + voffA, (DST) + w * 512);                                  \
        gload16(ab + 131072 + voffA, (DST) + 2048 + w * 512);                  \
    }

#define LOADB_HI(BH, t_)                                                       \
    {                                                                          \
        const char* bhp = BH0 + (size_t)(t_) * 163840;                         \
        _Pragma("unroll")                                                      \
        for (int g = 0; g < 5; g++) BH[g] = *(const s16x8*)(bhp + vB[g]);      \
    }

#define LOADB_LO(BL, t_)                                                       \
    {                                                                          \
        const char* blp = BL0 + (size_t)(t_) * 163840;                         \
        _Pragma("unroll")                                                      \
        for (int g = 0; g < 5; g++) BL[g] = *(const s16x8*)(blp + vB[g]);      \
    }

#define READ_AH(DST, ABASE)                                                    \
    {                                                                          \
        _Pragma("unroll")                                                      \
        for (int rf = 0; rf < 4; rf++)                                         \
            DST[rf] = *(const s16x8*)&(ABASE)[aoh + rf * 1024];                \
    }

#define READ_AL(DST, ABASE)                                                    \
    {                                                                          \
        _Pragma("unroll")                                                      \
        for (int rf = 0; rf < 4; rf++)                                         \
            DST[rf] = *(const s16x8*)&(ABASE)[aol + rf * 1024];                \
    }

// one pass: 20 independent MFMAs (acc[rf][g] each touched once)
#define MFMA_PASS(AREGS, BSET)                                                 \
    {                                                                          \
        __builtin_amdgcn_s_setprio(1);                                         \
        _Pragma("unroll")                                                      \
        for (int rf = 0; rf < 4; rf++)                                         \
            _Pragma("unroll")                                                  \
            for (int g = 0; g < 5; g++)                                        \
                acc[rf][g] = __builtin_amdgcn_mfma_f32_16x16x32_bf16(AREGS[rf], BSET[g], acc[rf][g], 0, 0, 0); \
        __builtin_amdgcn_s_setprio(0);                                         \
    }

// window: tiles T0 (frags preloaded in ah/al) and T1 (ahn + reused al); one counted barrier
#define WINDOW(ACUR, ANXT, t0_, more_)                                         \
    {                                                                          \
        if (more_) {                                                           \
            STAGEA2(ANXT, (t0_) + 2);                                          \
            STAGEA2((ANXT) + 4096, (t0_) + 3);                                 \
            __builtin_amdgcn_sched_barrier(0);                                 \
        }                                                                      \
        /* ---- T0 ---- */                                                     \
        MFMA_PASS(ah, b0h);                                                    \
        LOADB_HI(b1h, (t0_) + 1);                                              \
        MFMA_PASS(al, b0h);                                                    \
        LOADB_LO(b1l, (t0_) + 1);                                              \
        READ_AH(ahn, (ACUR) + 4096);        /* T1 hi frags under T0 pass3 */   \
        MFMA_PASS(ah, b0l);                                                    \
        /* ---- T1 ---- */                                                     \
        READ_AL(al, (ACUR) + 4096);         /* T1 lo frags under T1 pass1 */   \
        MFMA_PASS(ahn, b1h);                                                   \
        if (more_) LOADB_HI(b0h, (t0_) + 2);                                   \
        MFMA_PASS(al, b1h);                                                    \
        if (more_) LOADB_LO(b0l, (t0_) + 2);                                   \
        MFMA_PASS(ahn, b1l);                                                   \
        if (more_) {                                                           \
            asm volatile("s_waitcnt vmcnt(10)" ::: "memory");                  \
            __builtin_amdgcn_s_barrier();                                      \
            __builtin_amdgcn_sched_barrier(0);                                 \
            READ_AH(ah, ANXT);              /* next-window T0 frags */         \
            READ_AL(al, ANXT);                                                 \
        }                                                                      \
    }

    // ================= prologue =================
    STAGEA2(Ab0, 0);
    STAGEA2(Ab0 + 4096, 1);
    __builtin_amdgcn_sched_barrier(0);
    LOADB_HI(b0h, 0);
    LOADB_LO(b0l, 0);
    asm volatile("s_waitcnt vmcnt(10)" ::: "memory");
    __builtin_amdgcn_s_barrier();
    __builtin_amdgcn_sched_barrier(0);
    READ_AH(ah, Ab0);
    READ_AL(al, Ab0);

#pragma unroll 1
    for (int t0 = 0; t0 < NITER; t0 += 4) {
        WINDOW(Ab0, Ab1, t0, 1);
        WINDOW(Ab1, Ab0, t0 + 2, (t0 + 4 < NITER));
    }
#undef STAGEA2
#undef LOADB_HI
#undef LOADB_LO
#undef READ_AH
#undef READ_AL
#undef MFMA_PASS
#undef WINDOW

    // ================= fused LSTM epilogue =================
    const int jglob = j0 + wc * 16 + il;
    const float bi  = b_iou[jglob];
    const float bo_ = b_iou[512 + jglob];
    const float bu  = b_iou[1024 + jglob];
    const float bfl = b_f[jglob];
    const float bfr = b_f[512 + jglob];

#pragma unroll
    for (int rf = 0; rf < 4; rf++) {
#pragma unroll
        for (int r = 0; r < 4; r++) {
            const int m  = m0 + rf * 16 + kq * 4 + r;
            const int b  = m >> lgnp;
            const int p  = m & (np - 1);
            float i_ = acc[rf][0][r] + bi;
            float o_ = acc[rf][1][r] + bo_;
            float u_ = acc[rf][2][r] + bu;
            float fl = sigm(acc[rf][3][r] + bfl);
            float fr = sigm(acc[rf][4][r] + bfr);
            float cl = 0.0f, cr_ = 0.0f;
            if (!LEAF) {
                size_t cb_ = ((size_t)b * nc + 2 * p) * 512 + jglob;
                cl  = Cc[cb_];
                cr_ = Cc[cb_ + 512];
            }
            float cn = sigm(i_) * tanhf(u_) + fl * cl + fr * cr_;
            float hn = sigm(o_) * tanhf(cn);
            size_t prow = (size_t)b * np + p;
            u16 hh  = f2bf(hn);
            u16 hlo = f2bf(hn - bf2f(hh));
            Hp[prow * 1024 + (size_t)(jg * 4 + wc) * 32 + il]      = hh;
            Hp[prow * 1024 + (size_t)(jg * 4 + wc) * 32 + 16 + il] = hlo;
            Cp[prow * 512 + jglob] = cn;
        }
    }
}

// ---------------- small levels (np<64): R6 LDS-staged kernel + SGPR-ized B addressing ----------
__global__ __launch_bounds__(256, 2)
void level_small(const u16* __restrict__ Hc, const float* __restrict__ Cc,
                 const float* __restrict__ b_iou, const float* __restrict__ b_f,
                 u16* __restrict__ Hp, float* __restrict__ Cp,
                 int np, int lgnp)
{
    __shared__ __align__(16) u16 Ac[2][64 * ARW];

    const int tid = threadIdx.x;
    const int jg  = blockIdx.x;
    const int m0  = blockIdx.y * 64;
    const int j0  = jg * 64;
    const int nc  = np * 2;
    const int M   = np * 64;

    const int w    = tid >> 6;
    const int lane = tid & 63;
    const int il   = lane & 15;
    const int kq   = lane >> 4;
    const int wc   = w;

    f32x4 acc[4][5];
#pragma unroll
    for (int rf = 0; rf < 4; rf++)
#pragma unroll
        for (int g = 0; g < 5; g++) acc[rf][g] = (f32x4)0.0f;

    const int rA = tid >> 2;
    const int qA = tid & 3;
    int mA = m0 + rA; if (mA > M - 1) mA = M - 1;
    const int bA = mA >> lgnp;
    const int pA = mA & (np - 1);
    const u16* arow = Hc + ((size_t)bA * nc + 2 * pA) * 1024;
    const int daI = rA * ARW + (qA & 1) * 32 + (qA >> 1) * 16;

    const char* BH0 = (const char*)(g_Bhi + (size_t)j0 * 32);
    const char* BL0 = (const char*)(g_Blo + (size_t)j0 * 32);
    unsigned vB[5];
#pragma unroll
    for (int g = 0; g < 5; g++)
        vB[g] = (unsigned)(((wc * 16 + il) * 32 + kq * 8) * 2 + g * 32768);

    uint4  aR0, aR1;
    s16x8 b0h[5], b0l[5], b1h[5], b1l[5];

#define LOADA(t_)                                                              \
    {                                                                          \
        const u16* asrc = arow + (t_) * 64 + qA * 16;                          \
        aR0 = *(const uint4*)asrc;                                             \
        aR1 = *(const uint4*)(asrc + 8);                                       \
    }
#define LOADB(BH, BL, t_)                                                      \
    {                                                                          \
        const char* bh = BH0 + (size_t)(t_) * 163840;                          \
        const char* bl = BL0 + (size_t)(t_) * 163840;                          \
        _Pragma("unroll")                                                      \
        for (int g = 0; g < 5; g++) {                                          \
            BH[g] = *(const s16x8*)(bh + vB[g]);                               \
            BL[g] = *(const s16x8*)(bl + vB[g]);                               \
        }                                                                      \
    }
#define WRITEA(bf)                                                             \
    {                                                                          \
        *(uint4*)&Ac[bf][daI]     = aR0;                                       \
        *(uint4*)&Ac[bf][daI + 8] = aR1;                                       \
    }
#define COMPUTE(BH, BL, BUF)                                                   \
    {                                                                          \
        _Pragma("unroll")                                                      \
        for (int rf = 0; rf < 4; rf++) {                                       \
            const int ao = (rf * 16 + il) * ARW + kq * 8;                      \
            s16x8 ahv = *(const s16x8*)&Ac[BUF][ao];                           \
            s16x8 alv = *(const s16x8*)&Ac[BUF][ao + 32];                      \
            _Pragma("unroll")                                                  \
            for (int g = 0; g < 5; g++) {                                      \
                acc[rf][g] = __builtin_amdgcn_mfma_f32_16x16x32_bf16(ahv, BH[g], acc[rf][g], 0, 0, 0); \
                acc[rf][g] = __builtin_amdgcn_mfma_f32_16x16x32_bf16(ahv, BL[g], acc[rf][g], 0, 0, 0); \
                acc[rf][g] = __builtin_amdgcn_mfma_f32_16x16x32_bf16(alv, BH[g], acc[rf][g], 0, 0, 0); \
            }                                                                  \
        }                                                                      \
    }

    LOADA(0);
    LOADB(b0h, b0l, 0);
    WRITEA(0);
    __syncthreads();

#pragma unroll 1
    for (int t = 0; t < NITER; t += 2) {
        if (t + 1 < NITER) { LOADA(t + 1); LOADB(b1h, b1l, t + 1); }
        COMPUTE(b0h, b0l, 0);
        if (t + 1 < NITER) { WRITEA(1); __syncthreads(); }
        if (t + 2 < NITER) { LOADA(t + 2); LOADB(b0h, b0l, t + 2); }
        COMPUTE(b1h, b1l, 1);
        if (t + 2 < NITER) { WRITEA(0); __syncthreads(); }
    }
#undef LOADA
#undef LOADB
#undef WRITEA
#undef COMPUTE

    const int jglob = j0 + wc * 16 + il;
    const float bi  = b_iou[jglob];
    const float bo_ = b_iou[512 + jglob];
    const float bu  = b_iou[1024 + jglob];
    const float bfl = b_f[jglob];
    const float bfr = b_f[512 + jglob];

#pragma unroll
    for (int rf = 0; rf < 4; rf++) {
#pragma unroll
        for (int r = 0; r < 4; r++) {
            const int m = m0 + rf * 16 + kq * 4 + r;
            if (m < M) {
                const int b = m >> lgnp;
                const int p = m & (np - 1);
                float i_ = acc[rf][0][r] + bi;
                float o_ = acc[rf][1][r] + bo_;
                float u_ = acc[rf][2][r] + bu;
                float fl = sigm(acc[rf][3][r] + bfl);
                float fr = sigm(acc[rf][4][r] + bfr);
                size_t cb_ = ((size_t)b * nc + 2 * p) * 512 + jglob;
                float cl  = Cc[cb_];
                float cr_ = Cc[cb_ + 512];
                float cn = sigm(i_) * tanhf(u_) + fl * cl + fr * cr_;
                float hn = sigm(o_) * tanhf(cn);
                size_t prow = (size_t)b * np + p;
                u16 hh  = f2bf(hn);
                u16 hlo = f2bf(hn - bf2f(hh));
                Hp[prow * 1024 + (size_t)(jg * 4 + wc) * 32 + il]      = hh;
                Hp[prow * 1024 + (size_t)(jg * 4 + wc) * 32 + 16 + il] = hlo;
                Cp[prow * 512 + jglob] = cn;
            }
        }
    }
}

// ---------------- out[b][c] = sum_d h_root[b][d] * W_out[d][c] ----------------
__global__ __launch_bounds__(256)
void out_kernel(const u16* __restrict__ Hroot, const float* __restrict__ W_out,
                float* __restrict__ out)
{
    const int b = blockIdx.x;
    const int tid = threadIdx.x;
    float s0 = 0.f, s1 = 0.f;
    for (int d = tid; d < 512; d += 256) {
        const u16* row = Hroot + (size_t)b * 1024 + (d >> 4) * 32 + (d & 15);
        float h = bf2f(row[0]) + bf2f(row[16]);
        s0 = fmaf(h, W_out[d * 2 + 0], s0);
        s1 = fmaf(h, W_out[d * 2 + 1], s1);
    }
#pragma unroll
    for (int off = 32; off > 0; off >>= 1) {
        s0 += __shfl_down(s0, off, 64);
        s1 += __shfl_down(s1, off, 64);
    }
    __shared__ float red[2][4];
    const int wave = tid >> 6;
    if ((tid & 63) == 0) { red[0][wave] = s0; red[1][wave] = s1; }
    __syncthreads();
    if (tid == 0) {
        float t0 = 0.f, t1 = 0.f;
#pragma unroll
        for (int wv = 0; wv < 4; wv++) { t0 += red[0][wv]; t1 += red[1][wv]; }
        out[b * 2 + 0] = t0;
        out[b * 2 + 1] = t1;
    }
}

extern "C" void kernel_launch(void* const* d_in, const int* in_sizes, int n_in,
                              void* d_out, int out_size, void* d_ws, size_t ws_size,
                              hipStream_t stream)
{
    const int*   tokens = (const int*)  d_in[0];
    const float* emb    = (const float*)d_in[1];
    const float* W_iou  = (const float*)d_in[2];
    const float* b_iou  = (const float*)d_in[3];
    const float* W_f    = (const float*)d_in[4];
    const float* b_f    = (const float*)d_in[5];
    const float* W_out  = (const float*)d_in[6];
    float* out = (float*)d_out;

    // ws layout (201.3 MB, proven):
    u16*   H0 = (u16*)d_ws;
    float* C0 = (float*)(H0 + (size_t)512 * 64 * 1024);
    u16*   H1 = (u16*)(C0 + (size_t)512 * 64 * 512);
    float* C1 = (float*)(H1 + (size_t)256 * 64 * 1024);

    wsplit_kernel<<<dim3(32, 40), 256, 0, stream>>>(W_iou, W_f);
    leafgather_kernel<<<8192, 256, 0, stream>>>(tokens, emb);

    // level 9: leaves -> 512 parents (A = g_Aleaf, c = 0)
    level_big<true><<<dim3(8, 512), 256, 0, stream>>>(
        nullptr, nullptr, b_iou, b_f, H0, C0, 512, 9);

    u16* Hc = H0;  float* Cc = C0;
    u16* Hp = H1;  float* Cp = C1;
    for (int L = 8; L >= 0; L--) {
        const int np = 1 << L;
        if (np >= 64) {
            level_big<false><<<dim3(8, np), 256, 0, stream>>>(
                Hc, Cc, b_iou, b_f, Hp, Cp, np, L);
        } else {
            level_small<<<dim3(8, np), 256, 0, stream>>>(
                Hc, Cc, b_iou, b_f, Hp, Cp, np, L);
        }
        u16* tH = Hc; Hc = Hp; Hp = tH;
        float* tC = Cc; Cc = Cp; Cp = tC;
    }

    out_kernel<<<64, 256, 0, stream>>>(Hc, W_out, out);
}

// Round 15
// 1401.089 us; speedup vs baseline: 1.1771x; 1.1771x over previous
//
#include <hip/hip_runtime.h>
#include <math.h>

typedef unsigned short u16;
typedef short s16x8 __attribute__((ext_vector_type(8)));
typedef float f32x4 __attribute__((ext_vector_type(4)));

#define NITER 32   // K=1024 / BK=32 k-tiles
#define ARW 72     // u16 per A LDS row (small-level kernel only)

// Pre-split, transposed weights: layout [kb 32][gate 5][j 512][k 32]
__device__ __align__(16) u16 g_Bhi[1024 * 2560];
__device__ __align__(16) u16 g_Blo[1024 * 2560];
// Pre-split leaf A panel: row i -> split emb[tokens[i]] (1024 u16 = 32 chunks of [16hi|16lo])
__device__ __align__(16) u16 g_Aleaf[(size_t)64 * 1024 * 1024];

__device__ __forceinline__ u16 f2bf(float x) {
    unsigned u = __float_as_uint(x);
    u += 0x7fffu + ((u >> 16) & 1u);       // RNE
    return (u16)(u >> 16);
}
__device__ __forceinline__ float bf2f(u16 h) { return __uint_as_float(((unsigned)h) << 16); }
__device__ __forceinline__ float sigm(float x) { return 1.0f / (1.0f + expf(-x)); }
__device__ __forceinline__ unsigned pk(u16 a, u16 b) { return (unsigned)a | ((unsigned)b << 16); }

__device__ __forceinline__ void gload16(const void* g, u16* l) {
    __builtin_amdgcn_global_load_lds(
        (const __attribute__((address_space(1))) void*)g,
        (__attribute__((address_space(3))) void*)(void*)l, 16, 0, 0);
}

// ---------------- weight split+transpose: W[k][col] f32 -> [kb][g][j][k] bf16 hi/lo ----------
__global__ __launch_bounds__(256)
void wsplit_kernel(const float* __restrict__ Wiou, const float* __restrict__ Wf)
{
    __shared__ float tile[32][65];
    const int kb = blockIdx.x;           // 0..31
    const int cb = blockIdx.y;           // 0..39
    const int t  = threadIdx.x;
    const int c0 = cb * 64;

    {
        const int kk  = t >> 3;
        const int cu0 = (t & 7) * 8;
        const int k   = kb * 32 + kk;
#pragma unroll
        for (int u = 0; u < 8; u++) {
            int c = c0 + cu0 + u;
            float v = (c < 1536) ? Wiou[(size_t)k * 1536 + c]
                                 : Wf[(size_t)k * 1024 + (c - 1536)];
            tile[kk][cu0 + u] = v;
        }
    }
    __syncthreads();
    {
        const int jl = t >> 2;
        const int kc = (t & 3) * 8;
        const int g  = c0 >> 9;
        const int j  = (c0 & 511) + jl;
        size_t dst = (((size_t)kb * 5 + g) * 512 + j) * 32 + kc;
        unsigned ph[4], pl[4];
#pragma unroll
        for (int u = 0; u < 4; u++) {
            float v0 = tile[kc + 2 * u][jl];
            float v1 = tile[kc + 2 * u + 1][jl];
            u16 h0 = f2bf(v0), h1 = f2bf(v1);
            u16 l0 = f2bf(v0 - bf2f(h0)), l1 = f2bf(v1 - bf2f(h1));
            ph[u] = pk(h0, h1);
            pl[u] = pk(l0, l1);
        }
        *(uint4*)(g_Bhi + dst) = make_uint4(ph[0], ph[1], ph[2], ph[3]);
        *(uint4*)(g_Blo + dst) = make_uint4(pl[0], pl[1], pl[2], pl[3]);
    }
}

// ---------------- leaf A gather+split ----------------
__global__ __launch_bounds__(256)
void leafgather_kernel(const int* __restrict__ tokens, const float* __restrict__ emb)
{
    const int gidx = blockIdx.x * 256 + threadIdx.x;   // chunk id
    const int row  = gidx >> 5;
    const int c    = gidx & 31;
    const int tok  = tokens[row];
    const float* src = emb + (size_t)tok * 512 + c * 16;
    u16* dst = g_Aleaf + (size_t)row * 1024 + c * 32;

    float4 f0 = *(const float4*)(src);
    float4 f1 = *(const float4*)(src + 4);
    float4 f2 = *(const float4*)(src + 8);
    float4 f3 = *(const float4*)(src + 12);
    float v[16] = {f0.x,f0.y,f0.z,f0.w, f1.x,f1.y,f1.z,f1.w,
                   f2.x,f2.y,f2.z,f2.w, f3.x,f3.y,f3.z,f3.w};
    unsigned ph[8], pl[8];
#pragma unroll
    for (int i = 0; i < 8; i++) {
        u16 h0 = f2bf(v[2*i]),   h1 = f2bf(v[2*i+1]);
        u16 l0 = f2bf(v[2*i]   - bf2f(h0));
        u16 l1 = f2bf(v[2*i+1] - bf2f(h1));
        ph[i] = pk(h0, h1);
        pl[i] = pk(l0, l1);
    }
    *(uint4*)(dst)      = make_uint4(ph[0], ph[1], ph[2], ph[3]);
    *(uint4*)(dst + 8)  = make_uint4(ph[4], ph[5], ph[6], ph[7]);
    *(uint4*)(dst + 16) = make_uint4(pl[0], pl[1], pl[2], pl[3]);
    *(uint4*)(dst + 24) = make_uint4(pl[4], pl[5], pl[6], pl[7]);
}

// ---------------- big levels (np>=64): BK=64 windows + DUAL B register sets ---------------
// R13 window structure (16 barriers) with R10's dual-B register config: b0 serves even
// tiles, b1 serves odd tiles; each is reloaded 2 tiles before its next use (~390cy >> L2
// latency). Window barrier waits vmcnt(20) = exactly the 4 A gload_lds (issued first);
// all 20 B loads stay in flight across the barrier. Register envelope identical to R10
// (proven 128 VGPR, no spill).
template<bool LEAF>
__global__ __launch_bounds__(256, 2)
void level_big(const u16* __restrict__ Hcin, const float* __restrict__ Cc,
               const float* __restrict__ b_iou, const float* __restrict__ b_f,
               u16* __restrict__ Hp, float* __restrict__ Cp,
               int np, int lgnp)
{
    __shared__ __align__(16) u16 Ab0[8192];   // 16 KB: k-tiles {t0, t0+1}
    __shared__ __align__(16) u16 Ab1[8192];   // 16 KB: next window

    const u16* Hc = LEAF ? g_Aleaf : Hcin;

    const int tid = threadIdx.x;
    const int jg  = blockIdx.x;          // 0..7 -> XCD pinning via %8
    const int m0  = blockIdx.y * 64;
    const int j0  = jg * 64;
    const int nc  = np * 2;

    const int w    = tid >> 6;
    const int lane = tid & 63;
    const int il   = lane & 15;
    const int kq   = lane >> 4;
    const int wc   = w;                  // j sub-range wc*16 .. +15

    f32x4 acc[4][5];
#pragma unroll
    for (int rf = 0; rf < 4; rf++)
#pragma unroll
        for (int g = 0; g < 5; g++) acc[rf][g] = (f32x4)0.0f;

    // ---- A staging: uniform base + constant per-lane offset (swizzled source) ----
    const int bA  = m0 >> lgnp;
    const int pA0 = m0 & (np - 1);
    const char* A0u = (const char*)(Hc + ((size_t)bA * nc + 2 * pA0) * 1024);  // uniform
    const int rowS = tid >> 3;                       // A-row 0..31 (instr0), +32 (instr1)
    const int segS = (tid & 7) ^ (rowS & 7);         // swizzled source slot
    const unsigned voffA = (unsigned)rowS * 4096u + (unsigned)segS * 16u;      // bytes, const

    // ---- A read offsets (swizzled, per-thread constants) ----
    const int shi = ((kq >> 1) << 2) | (kq & 1);     // hi slot for this kq
    const int x7  = il & 7;
    const int aoh = il * 64 + ((shi ^ x7) * 8);
    const int aol = il * 64 + (((shi + 2) ^ x7) * 8);

    // ---- B: uniform bases + 5 constant per-thread offsets ----
    const char* BH0 = (const char*)(g_Bhi + (size_t)j0 * 32);   // uniform
    const char* BL0 = (const char*)(g_Blo + (size_t)j0 * 32);   // uniform
    unsigned vB[5];
#pragma unroll
    for (int g = 0; g < 5; g++)
        vB[g] = (unsigned)(((wc * 16 + il) * 32 + kq * 8) * 2 + g * 32768);

    // dual B register sets: b0 = even tiles, b1 = odd tiles
    s16x8 b0h[5], b0l[5], b1h[5], b1l[5];

#define STAGEA2(DST, t_)                                                       \
    {                                                                          \
        const char* ab = A0u + (size_t)(t_) * 128;                             \
        gload16(ab + voffA, (DST) + w * 512);                                  \
        gload16(ab + 131072 + voffA, (DST) + 2048 + w * 512);                  \
    }

#define LOADB_HI(BH, t_)                                                       \
    {                                                                          \
        const char* bhp = BH0 + (size_t)(t_) * 163840;                         \
        _Pragma("unroll")                                                      \
        for (int g = 0; g < 5; g++) BH[g] = *(const s16x8*)(bhp + vB[g]);      \
    }

#define LOADB_LO(BL, t_)                                                       \
    {                                                                          \
        const char* blp = BL0 + (size_t)(t_) * 163840;                         \
        _Pragma("unroll")                                                      \
        for (int g = 0; g < 5; g++) BL[g] = *(const s16x8*)(blp + vB[g]);      \
    }

// one pass: 20 independent MFMAs (acc[rf][g] each touched once)
#define MFMA_PASS(AREGS, BSET)                                                 \
    {                                                                          \
        __builtin_amdgcn_s_setprio(1);                                         \
        _Pragma("unroll")                                                      \
        for (int rf = 0; rf < 4; rf++)                                         \
            _Pragma("unroll")                                                  \
            for (int g = 0; g < 5; g++)                                        \
                acc[rf][g] = __builtin_amdgcn_mfma_f32_16x16x32_bf16(AREGS[rf], BSET[g], acc[rf][g], 0, 0, 0); \
        __builtin_amdgcn_s_setprio(0);                                         \
    }

// one k-tile: read A frags from LDS, 3 passes; reload the tile's own B set (for tile
// t+2, consumed next window) right after each half's last use
#define TILE_COMPUTE(ABASE, BH, BL, tload_, do_load_)                          \
    {                                                                          \
        s16x8 ah[4], al[4];                                                    \
        _Pragma("unroll")                                                      \
        for (int rf = 0; rf < 4; rf++) {                                       \
            ah[rf] = *(const s16x8*)&(ABASE)[aoh + rf * 1024];                 \
            al[rf] = *(const s16x8*)&(ABASE)[aol + rf * 1024];                 \
        }                                                                      \
        MFMA_PASS(ah, BH);                                                     \
        MFMA_PASS(al, BH);                                                     \
        if (do_load_) LOADB_HI(BH, tload_);                                    \
        MFMA_PASS(ah, BL);                                                     \
        if (do_load_) LOADB_LO(BL, tload_);                                    \
    }

// one window: stage next 2 A-tiles, compute 2 current tiles (b0 then b1), one counted
// barrier waiting only the A gloads (20 B loads remain in flight)
#define WINDOW(ACUR, ANXT, t0_, more_)                                         \
    {                                                                          \
        if (more_) {                                                           \
            STAGEA2(ANXT, (t0_) + 2);                                          \
            STAGEA2((ANXT) + 4096, (t0_) + 3);                                 \
            __builtin_amdgcn_sched_barrier(0);                                 \
        }                                                                      \
        TILE_COMPUTE(ACUR, b0h, b0l, (t0_) + 2, more_);                        \
        TILE_COMPUTE((ACUR) + 4096, b1h, b1l, (t0_) + 3, more_);               \
        if (more_) {                                                           \
            asm volatile("s_waitcnt vmcnt(20)" ::: "memory");                  \
            __builtin_amdgcn_s_barrier();                                      \
            __builtin_amdgcn_sched_barrier(0);                                 \
        }                                                                      \
    }

    // ================= prologue =================
    STAGEA2(Ab0, 0);
    STAGEA2(Ab0 + 4096, 1);
    __builtin_amdgcn_sched_barrier(0);
    LOADB_HI(b0h, 0);
    LOADB_LO(b0l, 0);
    LOADB_HI(b1h, 1);
    LOADB_LO(b1l, 1);
    asm volatile("s_waitcnt vmcnt(20)" ::: "memory");
    __builtin_amdgcn_s_barrier();
    __builtin_amdgcn_sched_barrier(0);

#pragma unroll 1
    for (int t0 = 0; t0 < NITER; t0 += 4) {
        WINDOW(Ab0, Ab1, t0, 1);
        WINDOW(Ab1, Ab0, t0 + 2, (t0 + 4 < NITER));
    }
#undef STAGEA2
#undef LOADB_HI
#undef LOADB_LO
#undef MFMA_PASS
#undef TILE_COMPUTE
#undef WINDOW

    // ================= fused LSTM epilogue =================
    const int jglob = j0 + wc * 16 + il;
    const float bi  = b_iou[jglob];
    const float bo_ = b_iou[512 + jglob];
    const float bu  = b_iou[1024 + jglob];
    const float bfl = b_f[jglob];
    const float bfr = b_f[512 + jglob];

#pragma unroll
    for (int rf = 0; rf < 4; rf++) {
#pragma unroll
        for (int r = 0; r < 4; r++) {
            const int m  = m0 + rf * 16 + kq * 4 + r;
            const int b  = m >> lgnp;
            const int p  = m & (np - 1);
            float i_ = acc[rf][0][r] + bi;
            float o_ = acc[rf][1][r] + bo_;
            float u_ = acc[rf][2][r] + bu;
            float fl = sigm(acc[rf][3][r] + bfl);
            float fr = sigm(acc[rf][4][r] + bfr);
            float cl = 0.0f, cr_ = 0.0f;
            if (!LEAF) {
                size_t cb_ = ((size_t)b * nc + 2 * p) * 512 + jglob;
                cl  = Cc[cb_];
                cr_ = Cc[cb_ + 512];
            }
            float cn = sigm(i_) * tanhf(u_) + fl * cl + fr * cr_;
            float hn = sigm(o_) * tanhf(cn);
            size_t prow = (size_t)b * np + p;
            u16 hh  = f2bf(hn);
            u16 hlo = f2bf(hn - bf2f(hh));
            Hp[prow * 1024 + (size_t)(jg * 4 + wc) * 32 + il]      = hh;
            Hp[prow * 1024 + (size_t)(jg * 4 + wc) * 32 + 16 + il] = hlo;
            Cp[prow * 512 + jglob] = cn;
        }
    }
}

// ---------------- small levels (np<64): R6 LDS-staged kernel + SGPR-ized B addressing ----------
__global__ __launch_bounds__(256, 2)
void level_small(const u16* __restrict__ Hc, const float* __restrict__ Cc,
                 const float* __restrict__ b_iou, const float* __restrict__ b_f,
                 u16* __restrict__ Hp, float* __restrict__ Cp,
                 int np, int lgnp)
{
    __shared__ __align__(16) u16 Ac[2][64 * ARW];

    const int tid = threadIdx.x;
    const int jg  = blockIdx.x;
    const int m0  = blockIdx.y * 64;
    const int j0  = jg * 64;
    const int nc  = np * 2;
    const int M   = np * 64;

    const int w    = tid >> 6;
    const int lane = tid & 63;
    const int il   = lane & 15;
    const int kq   = lane >> 4;
    const int wc   = w;

    f32x4 acc[4][5];
#pragma unroll
    for (int rf = 0; rf < 4; rf++)
#pragma unroll
        for (int g = 0; g < 5; g++) acc[rf][g] = (f32x4)0.0f;

    const int rA = tid >> 2;
    const int qA = tid & 3;
    int mA = m0 + rA; if (mA > M - 1) mA = M - 1;
    const int bA = mA >> lgnp;
    const int pA = mA & (np - 1);
    const u16* arow = Hc + ((size_t)bA * nc + 2 * pA) * 1024;
    const int daI = rA * ARW + (qA & 1) * 32 + (qA >> 1) * 16;

    const char* BH0 = (const char*)(g_Bhi + (size_t)j0 * 32);
    const char* BL0 = (const char*)(g_Blo + (size_t)j0 * 32);
    unsigned vB[5];
#pragma unroll
    for (int g = 0; g < 5; g++)
        vB[g] = (unsigned)(((wc * 16 + il) * 32 + kq * 8) * 2 + g * 32768);

    uint4  aR0, aR1;
    s16x8 b0h[5], b0l[5], b1h[5], b1l[5];

#define LOADA(t_)                                                              \
    {                                                                          \
        const u16* asrc = arow + (t_) * 64 + qA * 16;                          \
        aR0 = *(const uint4*)asrc;                                             \
        aR1 = *(const uint4*)(asrc + 8);                                       \
    }
#define LOADB(BH, BL, t_)                                                      \
    {                                                                          \
        const char* bh = BH0 + (size_t)(t_) * 163840;                          \
        const char* bl = BL0 + (size_t)(t_) * 163840;                          \
        _Pragma("unroll")                                                      \
        for (int g = 0; g < 5; g++) {                                          \
            BH[g] = *(const s16x8*)(bh + vB[g]);                               \
            BL[g] = *(const s16x8*)(bl + vB[g]);                               \
        }                                                                      \
    }
#define WRITEA(bf)                                                             \
    {                                                                          \
        *(uint4*)&Ac[bf][daI]     = aR0;                                       \
        *(uint4*)&Ac[bf][daI + 8] = aR1;                                       \
    }
#define COMPUTE(BH, BL, BUF)                                                   \
    {                                                                          \
        _Pragma("unroll")                                                      \
        for (int rf = 0; rf < 4; rf++) {                                       \
            const int ao = (rf * 16 + il) * ARW + kq * 8;                      \
            s16x8 ahv = *(const s16x8*)&Ac[BUF][ao];                           \
            s16x8 alv = *(const s16x8*)&Ac[BUF][ao + 32];                      \
            _Pragma("unroll")                                                  \
            for (int g = 0; g < 5; g++) {                                      \
                acc[rf][g] = __builtin_amdgcn_mfma_f32_16x16x32_bf16(ahv, BH[g], acc[rf][g], 0, 0, 0); \
                acc[rf][g] = __builtin_amdgcn_mfma_f32_16x16x32_bf16(ahv, BL[g], acc[rf][g], 0, 0, 0); \
                acc[rf][g] = __builtin_amdgcn_mfma_f32_16x16x32_bf16(alv, BH[g], acc[rf][g], 0, 0, 0); \
            }                                                                  \
        }                                                                      \
    }

    LOADA(0);
    LOADB(b0h, b0l, 0);
    WRITEA(0);
    __syncthreads();

#pragma unroll 1
    for (int t = 0; t < NITER; t += 2) {
        if (t + 1 < NITER) { LOADA(t + 1); LOADB(b1h, b1l, t + 1); }
        COMPUTE(b0h, b0l, 0);
        if (t + 1 < NITER) { WRITEA(1); __syncthreads(); }
        if (t + 2 < NITER) { LOADA(t + 2); LOADB(b0h, b0l, t + 2); }
        COMPUTE(b1h, b1l, 1);
        if (t + 2 < NITER) { WRITEA(0); __syncthreads(); }
    }
#undef LOADA
#undef LOADB
#undef WRITEA
#undef COMPUTE

    const int jglob = j0 + wc * 16 + il;
    const float bi  = b_iou[jglob];
    const float bo_ = b_iou[512 + jglob];
    const float bu  = b_iou[1024 + jglob];
    const float bfl = b_f[jglob];
    const float bfr = b_f[512 + jglob];

#pragma unroll
    for (int rf = 0; rf < 4; rf++) {
#pragma unroll
        for (int r = 0; r < 4; r++) {
            const int m = m0 + rf * 16 + kq * 4 + r;
            if (m < M) {
                const int b = m >> lgnp;
                const int p = m & (np - 1);
                float i_ = acc[rf][0][r] + bi;
                float o_ = acc[rf][1][r] + bo_;
                float u_ = acc[rf][2][r] + bu;
                float fl = sigm(acc[rf][3][r] + bfl);
                float fr = sigm(acc[rf][4][r] + bfr);
                size_t cb_ = ((size_t)b * nc + 2 * p) * 512 + jglob;
                float cl  = Cc[cb_];
                float cr_ = Cc[cb_ + 512];
                float cn = sigm(i_) * tanhf(u_) + fl * cl + fr * cr_;
                float hn = sigm(o_) * tanhf(cn);
                size_t prow = (size_t)b * np + p;
                u16 hh  = f2bf(hn);
                u16 hlo = f2bf(hn - bf2f(hh));
                Hp[prow * 1024 + (size_t)(jg * 4 + wc) * 32 + il]      = hh;
                Hp[prow * 1024 + (size_t)(jg * 4 + wc) * 32 + 16 + il] = hlo;
                Cp[prow * 512 + jglob] = cn;
            }
        }
    }
}

// ---------------- out[b][c] = sum_d h_root[b][d] * W_out[d][c] ----------------
__global__ __launch_bounds__(256)
void out_kernel(const u16* __restrict__ Hroot, const float* __restrict__ W_out,
                float* __restrict__ out)
{
    const int b = blockIdx.x;
    const int tid = threadIdx.x;
    float s0 = 0.f, s1 = 0.f;
    for (int d = tid; d < 512; d += 256) {
        const u16* row = Hroot + (size_t)b * 1024 + (d >> 4) * 32 + (d & 15);
        float h = bf2f(row[0]) + bf2f(row[16]);
        s0 = fmaf(h, W_out[d * 2 + 0], s0);
        s1 = fmaf(h, W_out[d * 2 + 1], s1);
    }
#pragma unroll
    for (int off = 32; off > 0; off >>= 1) {
        s0 += __shfl_down(s0, off, 64);
        s1 += __shfl_down(s1, off, 64);
    }
    __shared__ float red[2][4];
    const int wave = tid >> 6;
    if ((tid & 63) == 0) { red[0][wave] = s0; red[1][wave] = s1; }
    __syncthreads();
    if (tid == 0) {
        float t0 = 0.f, t1 = 0.f;
#pragma unroll
        for (int wv = 0; wv < 4; wv++) { t0 += red[0][wv]; t1 += red[1][wv]; }
        out[b * 2 + 0] = t0;
        out[b * 2 + 1] = t1;
    }
}

extern "C" void kernel_launch(void* const* d_in, const int* in_sizes, int n_in,
                              void* d_out, int out_size, void* d_ws, size_t ws_size,
                              hipStream_t stream)
{
    const int*   tokens = (const int*)  d_in[0];
    const float* emb    = (const float*)d_in[1];
    const float* W_iou  = (const float*)d_in[2];
    const float* b_iou  = (const float*)d_in[3];
    const float* W_f    = (const float*)d_in[4];
    const float* b_f    = (const float*)d_in[5];
    const float* W_out  = (const float*)d_in[6];
    float* out = (float*)d_out;

    // ws layout (201.3 MB, proven):
    u16*   H0 = (u16*)d_ws;
    float* C0 = (float*)(H0 + (size_t)512 * 64 * 1024);
    u16*   H1 = (u16*)(C0 + (size_t)512 * 64 * 512);
    float* C1 = (float*)(H1 + (size_t)256 * 64 * 1024);

    wsplit_kernel<<<dim3(32, 40), 256, 0, stream>>>(W_iou, W_f);
    leafgather_kernel<<<8192, 256, 0, stream>>>(tokens, emb);

    // level 9: leaves -> 512 parents (A = g_Aleaf, c = 0)
    level_big<true><<<dim3(8, 512), 256, 0, stream>>>(
        nullptr, nullptr, b_iou, b_f, H0, C0, 512, 9);

    u16* Hc = H0;  float* Cc = C0;
    u16* Hp = H1;  float* Cp = C1;
    for (int L = 8; L >= 0; L--) {
        const int np = 1 << L;
        if (np >= 64) {
            level_big<false><<<dim3(8, np), 256, 0, stream>>>(
                Hc, Cc, b_iou, b_f, Hp, Cp, np, L);
        } else {
            level_small<<<dim3(8, np), 256, 0, stream>>>(
                Hc, Cc, b_iou, b_f, Hp, Cp, np, L);
        }
        u16* tH = Hc; Hc = Hp; Hp = tH;
        float* tC = Cc; Cc = Cp; Cp = tC;
    }

    out_kernel<<<64, 256, 0, stream>>>(Hc, W_out, out);
}

// Round 16
// 1232.892 us; speedup vs baseline: 1.3377x; 1.1364x over previous
//
#include <hip/hip_runtime.h>
#include <math.h>

typedef unsigned short u16;
typedef short s16x8 __attribute__((ext_vector_type(8)));
typedef float f32x4 __attribute__((ext_vector_type(4)));

#define NITER 32   // K=1024 / BK=32 k-tiles
#define ARW 72     // u16 per A LDS row (small-level kernel only)

// Pre-split, transposed weights: layout [kb 32][gate 5][j 512][k 32]
__device__ __align__(16) u16 g_Bhi[1024 * 2560];
__device__ __align__(16) u16 g_Blo[1024 * 2560];
// Pre-split leaf A panel: row i -> split emb[tokens[i]] (1024 u16 = 32 chunks of [16hi|16lo])
__device__ __align__(16) u16 g_Aleaf[(size_t)64 * 1024 * 1024];

__device__ __forceinline__ u16 f2bf(float x) {
    unsigned u = __float_as_uint(x);
    u += 0x7fffu + ((u >> 16) & 1u);       // RNE
    return (u16)(u >> 16);
}
__device__ __forceinline__ float bf2f(u16 h) { return __uint_as_float(((unsigned)h) << 16); }
__device__ __forceinline__ float sigm(float x) { return 1.0f / (1.0f + expf(-x)); }
__device__ __forceinline__ unsigned pk(u16 a, u16 b) { return (unsigned)a | ((unsigned)b << 16); }

__device__ __forceinline__ void gload16(const void* g, u16* l) {
    __builtin_amdgcn_global_load_lds(
        (const __attribute__((address_space(1))) void*)g,
        (__attribute__((address_space(3))) void*)(void*)l, 16, 0, 0);
}

// ---------------- weight split+transpose: W[k][col] f32 -> [kb][g][j][k] bf16 hi/lo ----------
__global__ __launch_bounds__(256)
void wsplit_kernel(const float* __restrict__ Wiou, const float* __restrict__ Wf)
{
    __shared__ float tile[32][65];
    const int kb = blockIdx.x;           // 0..31
    const int cb = blockIdx.y;           // 0..39
    const int t  = threadIdx.x;
    const int c0 = cb * 64;

    {
        const int kk  = t >> 3;
        const int cu0 = (t & 7) * 8;
        const int k   = kb * 32 + kk;
#pragma unroll
        for (int u = 0; u < 8; u++) {
            int c = c0 + cu0 + u;
            float v = (c < 1536) ? Wiou[(size_t)k * 1536 + c]
                                 : Wf[(size_t)k * 1024 + (c - 1536)];
            tile[kk][cu0 + u] = v;
        }
    }
    __syncthreads();
    {
        const int jl = t >> 2;
        const int kc = (t & 3) * 8;
        const int g  = c0 >> 9;
        const int j  = (c0 & 511) + jl;
        size_t dst = (((size_t)kb * 5 + g) * 512 + j) * 32 + kc;
        unsigned ph[4], pl[4];
#pragma unroll
        for (int u = 0; u < 4; u++) {
            float v0 = tile[kc + 2 * u][jl];
            float v1 = tile[kc + 2 * u + 1][jl];
            u16 h0 = f2bf(v0), h1 = f2bf(v1);
            u16 l0 = f2bf(v0 - bf2f(h0)), l1 = f2bf(v1 - bf2f(h1));
            ph[u] = pk(h0, h1);
            pl[u] = pk(l0, l1);
        }
        *(uint4*)(g_Bhi + dst) = make_uint4(ph[0], ph[1], ph[2], ph[3]);
        *(uint4*)(g_Blo + dst) = make_uint4(pl[0], pl[1], pl[2], pl[3]);
    }
}

// ---------------- leaf A gather+split ----------------
__global__ __launch_bounds__(256)
void leafgather_kernel(const int* __restrict__ tokens, const float* __restrict__ emb)
{
    const int gidx = blockIdx.x * 256 + threadIdx.x;   // chunk id
    const int row  = gidx >> 5;
    const int c    = gidx & 31;
    const int tok  = tokens[row];
    const float* src = emb + (size_t)tok * 512 + c * 16;
    u16* dst = g_Aleaf + (size_t)row * 1024 + c * 32;

    float4 f0 = *(const float4*)(src);
    float4 f1 = *(const float4*)(src + 4);
    float4 f2 = *(const float4*)(src + 8);
    float4 f3 = *(const float4*)(src + 12);
    float v[16] = {f0.x,f0.y,f0.z,f0.w, f1.x,f1.y,f1.z,f1.w,
                   f2.x,f2.y,f2.z,f2.w, f3.x,f3.y,f3.z,f3.w};
    unsigned ph[8], pl[8];
#pragma unroll
    for (int i = 0; i < 8; i++) {
        u16 h0 = f2bf(v[2*i]),   h1 = f2bf(v[2*i+1]);
        u16 l0 = f2bf(v[2*i]   - bf2f(h0));
        u16 l1 = f2bf(v[2*i+1] - bf2f(h1));
        ph[i] = pk(h0, h1);
        pl[i] = pk(l0, l1);
    }
    *(uint4*)(dst)      = make_uint4(ph[0], ph[1], ph[2], ph[3]);
    *(uint4*)(dst + 8)  = make_uint4(ph[4], ph[5], ph[6], ph[7]);
    *(uint4*)(dst + 16) = make_uint4(pl[0], pl[1], pl[2], pl[3]);
    *(uint4*)(dst + 24) = make_uint4(pl[4], pl[5], pl[6], pl[7]);
}

// ---------------- big levels (np>=64): BK=64 windows + in-place A-frag prefetch -----------
// R13 structure (16 barriers, single bh/bl set reloaded after last use) with T1's A-frags
// read IN PLACE mid-T0 (al after T0-pass2 when old al is dead; ah after T0-pass3), and T1
// run in rotated pass order (al*bh, ah*bh, ah*bl) so each freshly loaded operand gets a
// >=1-pass gap. Zero additional register liveness vs R13 (dead-value overwrite).
template<bool LEAF>
__global__ __launch_bounds__(256, 2)
void level_big(const u16* __restrict__ Hcin, const float* __restrict__ Cc,
               const float* __restrict__ b_iou, const float* __restrict__ b_f,
               u16* __restrict__ Hp, float* __restrict__ Cp,
               int np, int lgnp)
{
    __shared__ __align__(16) u16 Ab0[8192];   // 16 KB: k-tiles {t0, t0+1}
    __shared__ __align__(16) u16 Ab1[8192];   // 16 KB: next window

    const u16* Hc = LEAF ? g_Aleaf : Hcin;

    const int tid = threadIdx.x;
    const int jg  = blockIdx.x;          // 0..7 -> XCD pinning via %8
    const int m0  = blockIdx.y * 64;
    const int j0  = jg * 64;
    const int nc  = np * 2;

    const int w    = tid >> 6;
    const int lane = tid & 63;
    const int il   = lane & 15;
    const int kq   = lane >> 4;
    const int wc   = w;                  // j sub-range wc*16 .. +15

    f32x4 acc[4][5];
#pragma unroll
    for (int rf = 0; rf < 4; rf++)
#pragma unroll
        for (int g = 0; g < 5; g++) acc[rf][g] = (f32x4)0.0f;

    // ---- A staging: uniform base + constant per-lane offset (swizzled source) ----
    const int bA  = m0 >> lgnp;
    const int pA0 = m0 & (np - 1);
    const char* A0u = (const char*)(Hc + ((size_t)bA * nc + 2 * pA0) * 1024);  // uniform
    const int rowS = tid >> 3;                       // A-row 0..31 (instr0), +32 (instr1)
    const int segS = (tid & 7) ^ (rowS & 7);         // swizzled source slot
    const unsigned voffA = (unsigned)rowS * 4096u + (unsigned)segS * 16u;      // bytes, const

    // ---- A read offsets (swizzled, per-thread constants) ----
    const int shi = ((kq >> 1) << 2) | (kq & 1);     // hi slot for this kq
    const int x7  = il & 7;
    const int aoh = il * 64 + ((shi ^ x7) * 8);
    const int aol = il * 64 + (((shi + 2) ^ x7) * 8);

    // ---- B: uniform bases + 5 constant per-thread offsets ----
    const char* BH0 = (const char*)(g_Bhi + (size_t)j0 * 32);   // uniform
    const char* BL0 = (const char*)(g_Blo + (size_t)j0 * 32);   // uniform
    unsigned vB[5];
#pragma unroll
    for (int g = 0; g < 5; g++)
        vB[g] = (unsigned)(((wc * 16 + il) * 32 + kq * 8) * 2 + g * 32768);

    // single B set (reload-after-last-use) + persistent in-place A frags
    s16x8 bh[5], bl[5];
    s16x8 ah[4], al[4];

#define STAGEA2(DST, t_)                                                       \
    {                                                                          \
        const char* ab = A0u + (size_t)(t_) * 128;                             \
        gload16(ab + voffA, (DST) + w * 512);                                  \
        gload16(ab + 131072 + voffA, (DST) + 2048 + w * 512);                  \
    }

#define LOADB_HI(t_)                                                           \
    {                                                                          \
        const char* bhp = BH0 + (size_t)(t_) * 163840;                         \
        _Pragma("unroll")                                                      \
        for (int g = 0; g < 5; g++) bh[g] = *(const s16x8*)(bhp + vB[g]);      \
    }

#define LOADB_LO(t_)                                                           \
    {                                                                          \
        const char* blp = BL0 + (size_t)(t_) * 163840;                         \
        _Pragma("unroll")                                                      \
        for (int g = 0; g < 5; g++) bl[g] = *(const s16x8*)(blp + vB[g]);      \
    }

#define READ_AH(ABASE)                                                         \
    {                                                                          \
        _Pragma("unroll")                                                      \
        for (int rf = 0; rf < 4; rf++)                                         \
            ah[rf] = *(const s16x8*)&(ABASE)[aoh + rf * 1024];                 \
    }

#define READ_AL(ABASE)                                                         \
    {                                                                          \
        _Pragma("unroll")                                                      \
        for (int rf = 0; rf < 4; rf++)                                         \
            al[rf] = *(const s16x8*)&(ABASE)[aol + rf * 1024];                 \
    }

// one pass: 20 independent MFMAs (acc[rf][g] each touched once)
#define MFMA_PASS(AREGS, BSET)                                                 \
    {                                                                          \
        __builtin_amdgcn_s_setprio(1);                                         \
        _Pragma("unroll")                                                      \
        for (int rf = 0; rf < 4; rf++)                                         \
            _Pragma("unroll")                                                  \
            for (int g = 0; g < 5; g++)                                        \
                acc[rf][g] = __builtin_amdgcn_mfma_f32_16x16x32_bf16(AREGS[rf], BSET[g], acc[rf][g], 0, 0, 0); \
        __builtin_amdgcn_s_setprio(0);                                         \
    }

// one window: stage next 2 A-tiles; T0 with preloaded frags; T1 frags read in place
// mid-T0 (dead-value overwrite); rotated T1 pass order; one counted barrier
#define WINDOW(ACUR, ANXT, t0_, more_)                                         \
    {                                                                          \
        if (more_) {                                                           \
            STAGEA2(ANXT, (t0_) + 2);                                          \
            STAGEA2((ANXT) + 4096, (t0_) + 3);                                 \
            __builtin_amdgcn_sched_barrier(0);                                 \
        }                                                                      \
        /* ---- T0 (frags already in ah/al) ---- */                            \
        MFMA_PASS(ah, bh);                                                     \
        MFMA_PASS(al, bh);                   /* al, bh now dead */             \
        LOADB_HI((t0_) + 1);                                                   \
        READ_AL((ACUR) + 4096);              /* T1 lo frags, in place */       \
        MFMA_PASS(ah, bl);                   /* ah, bl now dead */             \
        LOADB_LO((t0_) + 1);                                                   \
        READ_AH((ACUR) + 4096);              /* T1 hi frags, in place */       \
        /* ---- T1 (rotated: al first) ---- */                                 \
        MFMA_PASS(al, bh);                                                     \
        MFMA_PASS(ah, bh);                   /* bh dead */                     \
        if (more_) LOADB_HI((t0_) + 2);                                        \
        MFMA_PASS(ah, bl);                   /* bl dead */                     \
        if (more_) LOADB_LO((t0_) + 2);                                        \
        if (more_) {                                                           \
            asm volatile("s_waitcnt vmcnt(10)" ::: "memory");                  \
            __builtin_amdgcn_s_barrier();                                      \
            __builtin_amdgcn_sched_barrier(0);                                 \
            READ_AH(ANXT);                   /* next-window T0 frags */        \
            READ_AL(ANXT);                                                     \
        }                                                                      \
    }

    // ================= prologue =================
    STAGEA2(Ab0, 0);
    STAGEA2(Ab0 + 4096, 1);
    __builtin_amdgcn_sched_barrier(0);
    LOADB_HI(0);
    LOADB_LO(0);
    asm volatile("s_waitcnt vmcnt(10)" ::: "memory");
    __builtin_amdgcn_s_barrier();
    __builtin_amdgcn_sched_barrier(0);
    READ_AH(Ab0);
    READ_AL(Ab0);

#pragma unroll 1
    for (int t0 = 0; t0 < NITER; t0 += 4) {
        WINDOW(Ab0, Ab1, t0, 1);
        WINDOW(Ab1, Ab0, t0 + 2, (t0 + 4 < NITER));
    }
#undef STAGEA2
#undef LOADB_HI
#undef LOADB_LO
#undef READ_AH
#undef READ_AL
#undef MFMA_PASS
#undef WINDOW

    // ================= fused LSTM epilogue =================
    const int jglob = j0 + wc * 16 + il;
    const float bi  = b_iou[jglob];
    const float bo_ = b_iou[512 + jglob];
    const float bu  = b_iou[1024 + jglob];
    const float bfl = b_f[jglob];
    const float bfr = b_f[512 + jglob];

#pragma unroll
    for (int rf = 0; rf < 4; rf++) {
#pragma unroll
        for (int r = 0; r < 4; r++) {
            const int m  = m0 + rf * 16 + kq * 4 + r;
            const int b  = m >> lgnp;
            const int p  = m & (np - 1);
            float i_ = acc[rf][0][r] + bi;
            float o_ = acc[rf][1][r] + bo_;
            float u_ = acc[rf][2][r] + bu;
            float fl = sigm(acc[rf][3][r] + bfl);
            float fr = sigm(acc[rf][4][r] + bfr);
            float cl = 0.0f, cr_ = 0.0f;
            if (!LEAF) {
                size_t cb_ = ((size_t)b * nc + 2 * p) * 512 + jglob;
                cl  = Cc[cb_];
                cr_ = Cc[cb_ + 512];
            }
            float cn = sigm(i_) * tanhf(u_) + fl * cl + fr * cr_;
            float hn = sigm(o_) * tanhf(cn);
            size_t prow = (size_t)b * np + p;
            u16 hh  = f2bf(hn);
            u16 hlo = f2bf(hn - bf2f(hh));
            Hp[prow * 1024 + (size_t)(jg * 4 + wc) * 32 + il]      = hh;
            Hp[prow * 1024 + (size_t)(jg * 4 + wc) * 32 + 16 + il] = hlo;
            Cp[prow * 512 + jglob] = cn;
        }
    }
}

// ---------------- small levels (np<64): R6 LDS-staged kernel + SGPR-ized B addressing ----------
__global__ __launch_bounds__(256, 2)
void level_small(const u16* __restrict__ Hc, const float* __restrict__ Cc,
                 const float* __restrict__ b_iou, const float* __restrict__ b_f,
                 u16* __restrict__ Hp, float* __restrict__ Cp,
                 int np, int lgnp)
{
    __shared__ __align__(16) u16 Ac[2][64 * ARW];

    const int tid = threadIdx.x;
    const int jg  = blockIdx.x;
    const int m0  = blockIdx.y * 64;
    const int j0  = jg * 64;
    const int nc  = np * 2;
    const int M   = np * 64;

    const int w    = tid >> 6;
    const int lane = tid & 63;
    const int il   = lane & 15;
    const int kq   = lane >> 4;
    const int wc   = w;

    f32x4 acc[4][5];
#pragma unroll
    for (int rf = 0; rf < 4; rf++)
#pragma unroll
        for (int g = 0; g < 5; g++) acc[rf][g] = (f32x4)0.0f;

    const int rA = tid >> 2;
    const int qA = tid & 3;
    int mA = m0 + rA; if (mA > M - 1) mA = M - 1;
    const int bA = mA >> lgnp;
    const int pA = mA & (np - 1);
    const u16* arow = Hc + ((size_t)bA * nc + 2 * pA) * 1024;
    const int daI = rA * ARW + (qA & 1) * 32 + (qA >> 1) * 16;

    const char* BH0 = (const char*)(g_Bhi + (size_t)j0 * 32);
    const char* BL0 = (const char*)(g_Blo + (size_t)j0 * 32);
    unsigned vB[5];
#pragma unroll
    for (int g = 0; g < 5; g++)
        vB[g] = (unsigned)(((wc * 16 + il) * 32 + kq * 8) * 2 + g * 32768);

    uint4  aR0, aR1;
    s16x8 b0h[5], b0l[5], b1h[5], b1l[5];

#define LOADA(t_)                                                              \
    {                                                                          \
        const u16* asrc = arow + (t_) * 64 + qA * 16;                          \
        aR0 = *(const uint4*)asrc;                                             \
        aR1 = *(const uint4*)(asrc + 8);                                       \
    }
#define LOADB(BH, BL, t_)                                                      \
    {                                                                          \
        const char* bh = BH0 + (size_t)(t_) * 163840;                          \
        const char* bl = BL0 + (size_t)(t_) * 163840;                          \
        _Pragma("unroll")                                                      \
        for (int g = 0; g < 5; g++) {                                          \
            BH[g] = *(const s16x8*)(bh + vB[g]);                               \
            BL[g] = *(const s16x8*)(bl + vB[g]);                               \
        }                                                                      \
    }
#define WRITEA(bf)                                                             \
    {                                                                          \
        *(uint4*)&Ac[bf][daI]     = aR0;                                       \
        *(uint4*)&Ac[bf][daI + 8] = aR1;                                       \
    }
#define COMPUTE(BH, BL, BUF)                                                   \
    {                                                                          \
        _Pragma("unroll")                                                      \
        for (int rf = 0; rf < 4; rf++) {                                       \
            const int ao = (rf * 16 + il) * ARW + kq * 8;                      \
            s16x8 ahv = *(const s16x8*)&Ac[BUF][ao];                           \
            s16x8 alv = *(const s16x8*)&Ac[BUF][ao + 32];                      \
            _Pragma("unroll")                                                  \
            for (int g = 0; g < 5; g++) {                                      \
                acc[rf][g] = __builtin_amdgcn_mfma_f32_16x16x32_bf16(ahv, BH[g], acc[rf][g], 0, 0, 0); \
                acc[rf][g] = __builtin_amdgcn_mfma_f32_16x16x32_bf16(ahv, BL[g], acc[rf][g], 0, 0, 0); \
                acc[rf][g] = __builtin_amdgcn_mfma_f32_16x16x32_bf16(alv, BH[g], acc[rf][g], 0, 0, 0); \
            }                                                                  \
        }                                                                      \
    }

    LOADA(0);
    LOADB(b0h, b0l, 0);
    WRITEA(0);
    __syncthreads();

#pragma unroll 1
    for (int t = 0; t < NITER; t += 2) {
        if (t + 1 < NITER) { LOADA(t + 1); LOADB(b1h, b1l, t + 1); }
        COMPUTE(b0h, b0l, 0);
        if (t + 1 < NITER) { WRITEA(1); __syncthreads(); }
        if (t + 2 < NITER) { LOADA(t + 2); LOADB(b0h, b0l, t + 2); }
        COMPUTE(b1h, b1l, 1);
        if (t + 2 < NITER) { WRITEA(0); __syncthreads(); }
    }
#undef LOADA
#undef LOADB
#undef WRITEA
#undef COMPUTE

    const int jglob = j0 + wc * 16 + il;
    const float bi  = b_iou[jglob];
    const float bo_ = b_iou[512 + jglob];
    const float bu  = b_iou[1024 + jglob];
    const float bfl = b_f[jglob];
    const float bfr = b_f[512 + jglob];

#pragma unroll
    for (int rf = 0; rf < 4; rf++) {
#pragma unroll
        for (int r = 0; r < 4; r++) {
            const int m = m0 + rf * 16 + kq * 4 + r;
            if (m < M) {
                const int b = m >> lgnp;
                const int p = m & (np - 1);
                float i_ = acc[rf][0][r] + bi;
                float o_ = acc[rf][1][r] + bo_;
                float u_ = acc[rf][2][r] + bu;
                float fl = sigm(acc[rf][3][r] + bfl);
                float fr = sigm(acc[rf][4][r] + bfr);
                size_t cb_ = ((size_t)b * nc + 2 * p) * 512 + jglob;
                float cl  = Cc[cb_];
                float cr_ = Cc[cb_ + 512];
                float cn = sigm(i_) * tanhf(u_) + fl * cl + fr * cr_;
                float hn = sigm(o_) * tanhf(cn);
                size_t prow = (size_t)b * np + p;
                u16 hh  = f2bf(hn);
                u16 hlo = f2bf(hn - bf2f(hh));
                Hp[prow * 1024 + (size_t)(jg * 4 + wc) * 32 + il]      = hh;
                Hp[prow * 1024 + (size_t)(jg * 4 + wc) * 32 + 16 + il] = hlo;
                Cp[prow * 512 + jglob] = cn;
            }
        }
    }
}

// ---------------- out[b][c] = sum_d h_root[b][d] * W_out[d][c] ----------------
__global__ __launch_bounds__(256)
void out_kernel(const u16* __restrict__ Hroot, const float* __restrict__ W_out,
                float* __restrict__ out)
{
    const int b = blockIdx.x;
    const int tid = threadIdx.x;
    float s0 = 0.f, s1 = 0.f;
    for (int d = tid; d < 512; d += 256) {
        const u16* row = Hroot + (size_t)b * 1024 + (d >> 4) * 32 + (d & 15);
        float h = bf2f(row[0]) + bf2f(row[16]);
        s0 = fmaf(h, W_out[d * 2 + 0], s0);
        s1 = fmaf(h, W_out[d * 2 + 1], s1);
    }
#pragma unroll
    for (int off = 32; off > 0; off >>= 1) {
        s0 += __shfl_down(s0, off, 64);
        s1 += __shfl_down(s1, off, 64);
    }
    __shared__ float red[2][4];
    const int wave = tid >> 6;
    if ((tid & 63) == 0) { red[0][wave] = s0; red[1][wave] = s1; }
    __syncthreads();
    if (tid == 0) {
        float t0 = 0.f, t1 = 0.f;
#pragma unroll
        for (int wv = 0; wv < 4; wv++) { t0 += red[0][wv]; t1 += red[1][wv]; }
        out[b * 2 + 0] = t0;
        out[b * 2 + 1] = t1;
    }
}

extern "C" void kernel_launch(void* const* d_in, const int* in_sizes, int n_in,
                              void* d_out, int out_size, void* d_ws, size_t ws_size,
                              hipStream_t stream)
{
    const int*   tokens = (const int*)  d_in[0];
    const float* emb    = (const float*)d_in[1];
    const float* W_iou  = (const float*)d_in[2];
    const float* b_iou  = (const float*)d_in[3];
    const float* W_f    = (const float*)d_in[4];
    const float* b_f    = (const float*)d_in[5];
    const float* W_out  = (const float*)d_in[6];
    float* out = (float*)d_out;

    // ws layout (201.3 MB, proven):
    u16*   H0 = (u16*)d_ws;
    float* C0 = (float*)(H0 + (size_t)512 * 64 * 1024);
    u16*   H1 = (u16*)(C0 + (size_t)512 * 64 * 512);
    float* C1 = (float*)(H1 + (size_t)256 * 64 * 1024);

    wsplit_kernel<<<dim3(32, 40), 256, 0, stream>>>(W_iou, W_f);
    leafgather_kernel<<<8192, 256, 0, stream>>>(tokens, emb);

    // level 9: leaves -> 512 parents (A = g_Aleaf, c = 0)
    level_big<true><<<dim3(8, 512), 256, 0, stream>>>(
        nullptr, nullptr, b_iou, b_f, H0, C0, 512, 9);

    u16* Hc = H0;  float* Cc = C0;
    u16* Hp = H1;  float* Cp = C1;
    for (int L = 8; L >= 0; L--) {
        const int np = 1 << L;
        if (np >= 64) {
            level_big<false><<<dim3(8, np), 256, 0, stream>>>(
                Hc, Cc, b_iou, b_f, Hp, Cp, np, L);
        } else {
            level_small<<<dim3(8, np), 256, 0, stream>>>(
                Hc, Cc, b_iou, b_f, Hp, Cp, np, L);
        }
        u16* tH = Hc; Hc = Hp; Hp = tH;
        float* tC = Cc; Cc = Cp; Cp = tC;
    }

    out_kernel<<<64, 256, 0, stream>>>(Hc, W_out, out);
}

// Round 17
// 1173.190 us; speedup vs baseline: 1.4057x; 1.0509x over previous
//
#include <hip/hip_runtime.h>
#include <math.h>

typedef unsigned short u16;
typedef short s16x8 __attribute__((ext_vector_type(8)));
typedef float f32x4 __attribute__((ext_vector_type(4)));

#define NITER 32   // K=1024 / BK=32 k-tiles

// Pre-split, transposed weights: layout [kb 32][gate 5][j 512][k 32]
__device__ __align__(16) u16 g_Bhi[1024 * 2560];
__device__ __align__(16) u16 g_Blo[1024 * 2560];
// Pre-split leaf A panel: row i -> split emb[tokens[i]] (1024 u16 = 32 chunks of [16hi|16lo])
__device__ __align__(16) u16 g_Aleaf[(size_t)64 * 1024 * 1024];

__device__ __forceinline__ u16 f2bf(float x) {
    unsigned u = __float_as_uint(x);
    u += 0x7fffu + ((u >> 16) & 1u);       // RNE
    return (u16)(u >> 16);
}
__device__ __forceinline__ float bf2f(u16 h) { return __uint_as_float(((unsigned)h) << 16); }
__device__ __forceinline__ float sigm(float x) { return 1.0f / (1.0f + expf(-x)); }
__device__ __forceinline__ unsigned pk(u16 a, u16 b) { return (unsigned)a | ((unsigned)b << 16); }

__device__ __forceinline__ void gload16(const void* g, u16* l) {
    __builtin_amdgcn_global_load_lds(
        (const __attribute__((address_space(1))) void*)g,
        (__attribute__((address_space(3))) void*)(void*)l, 16, 0, 0);
}

// ---------------- weight split+transpose: W[k][col] f32 -> [kb][g][j][k] bf16 hi/lo ----------
__global__ __launch_bounds__(256)
void wsplit_kernel(const float* __restrict__ Wiou, const float* __restrict__ Wf)
{
    __shared__ float tile[32][65];
    const int kb = blockIdx.x;           // 0..31
    const int cb = blockIdx.y;           // 0..39
    const int t  = threadIdx.x;
    const int c0 = cb * 64;

    {
        const int kk  = t >> 3;
        const int cu0 = (t & 7) * 8;
        const int k   = kb * 32 + kk;
#pragma unroll
        for (int u = 0; u < 8; u++) {
            int c = c0 + cu0 + u;
            float v = (c < 1536) ? Wiou[(size_t)k * 1536 + c]
                                 : Wf[(size_t)k * 1024 + (c - 1536)];
            tile[kk][cu0 + u] = v;
        }
    }
    __syncthreads();
    {
        const int jl = t >> 2;
        const int kc = (t & 3) * 8;
        const int g  = c0 >> 9;
        const int j  = (c0 & 511) + jl;
        size_t dst = (((size_t)kb * 5 + g) * 512 + j) * 32 + kc;
        unsigned ph[4], pl[4];
#pragma unroll
        for (int u = 0; u < 4; u++) {
            float v0 = tile[kc + 2 * u][jl];
            float v1 = tile[kc + 2 * u + 1][jl];
            u16 h0 = f2bf(v0), h1 = f2bf(v1);
            u16 l0 = f2bf(v0 - bf2f(h0)), l1 = f2bf(v1 - bf2f(h1));
            ph[u] = pk(h0, h1);
            pl[u] = pk(l0, l1);
        }
        *(uint4*)(g_Bhi + dst) = make_uint4(ph[0], ph[1], ph[2], ph[3]);
        *(uint4*)(g_Blo + dst) = make_uint4(pl[0], pl[1], pl[2], pl[3]);
    }
}

// ---------------- leaf A gather+split ----------------
__global__ __launch_bounds__(256)
void leafgather_kernel(const int* __restrict__ tokens, const float* __restrict__ emb)
{
    const int gidx = blockIdx.x * 256 + threadIdx.x;   // chunk id
    const int row  = gidx >> 5;
    const int c    = gidx & 31;
    const int tok  = tokens[row];
    const float* src = emb + (size_t)tok * 512 + c * 16;
    u16* dst = g_Aleaf + (size_t)row * 1024 + c * 32;

    float4 f0 = *(const float4*)(src);
    float4 f1 = *(const float4*)(src + 4);
    float4 f2 = *(const float4*)(src + 8);
    float4 f3 = *(const float4*)(src + 12);
    float v[16] = {f0.x,f0.y,f0.z,f0.w, f1.x,f1.y,f1.z,f1.w,
                   f2.x,f2.y,f2.z,f2.w, f3.x,f3.y,f3.z,f3.w};
    unsigned ph[8], pl[8];
#pragma unroll
    for (int i = 0; i < 8; i++) {
        u16 h0 = f2bf(v[2*i]),   h1 = f2bf(v[2*i+1]);
        u16 l0 = f2bf(v[2*i]   - bf2f(h0));
        u16 l1 = f2bf(v[2*i+1] - bf2f(h1));
        ph[i] = pk(h0, h1);
        pl[i] = pk(l0, l1);
    }
    *(uint4*)(dst)      = make_uint4(ph[0], ph[1], ph[2], ph[3]);
    *(uint4*)(dst + 8)  = make_uint4(ph[4], ph[5], ph[6], ph[7]);
    *(uint4*)(dst + 16) = make_uint4(pl[0], pl[1], pl[2], pl[3]);
    *(uint4*)(dst + 24) = make_uint4(pl[4], pl[5], pl[6], pl[7]);
}

// ---------------- big levels (np>=64): R16 kernel, UNCHANGED (proven best) ----------------
template<bool LEAF>
__global__ __launch_bounds__(256, 2)
void level_big(const u16* __restrict__ Hcin, const float* __restrict__ Cc,
               const float* __restrict__ b_iou, const float* __restrict__ b_f,
               u16* __restrict__ Hp, float* __restrict__ Cp,
               int np, int lgnp)
{
    __shared__ __align__(16) u16 Ab0[8192];   // 16 KB: k-tiles {t0, t0+1}
    __shared__ __align__(16) u16 Ab1[8192];   // 16 KB: next window

    const u16* Hc = LEAF ? g_Aleaf : Hcin;

    const int tid = threadIdx.x;
    const int jg  = blockIdx.x;          // 0..7 -> XCD pinning via %8
    const int m0  = blockIdx.y * 64;
    const int j0  = jg * 64;
    const int nc  = np * 2;

    const int w    = tid >> 6;
    const int lane = tid & 63;
    const int il   = lane & 15;
    const int kq   = lane >> 4;
    const int wc   = w;                  // j sub-range wc*16 .. +15

    f32x4 acc[4][5];
#pragma unroll
    for (int rf = 0; rf < 4; rf++)
#pragma unroll
        for (int g = 0; g < 5; g++) acc[rf][g] = (f32x4)0.0f;

    const int bA  = m0 >> lgnp;
    const int pA0 = m0 & (np - 1);
    const char* A0u = (const char*)(Hc + ((size_t)bA * nc + 2 * pA0) * 1024);  // uniform
    const int rowS = tid >> 3;
    const int segS = (tid & 7) ^ (rowS & 7);
    const unsigned voffA = (unsigned)rowS * 4096u + (unsigned)segS * 16u;

    const int shi = ((kq >> 1) << 2) | (kq & 1);
    const int x7  = il & 7;
    const int aoh = il * 64 + ((shi ^ x7) * 8);
    const int aol = il * 64 + (((shi + 2) ^ x7) * 8);

    const char* BH0 = (const char*)(g_Bhi + (size_t)j0 * 32);
    const char* BL0 = (const char*)(g_Blo + (size_t)j0 * 32);
    unsigned vB[5];
#pragma unroll
    for (int g = 0; g < 5; g++)
        vB[g] = (unsigned)(((wc * 16 + il) * 32 + kq * 8) * 2 + g * 32768);

    s16x8 bh[5], bl[5];
    s16x8 ah[4], al[4];

#define STAGEA2(DST, t_)                                                       \
    {                                                                          \
        const char* ab = A0u + (size_t)(t_) * 128;                             \
        gload16(ab + voffA, (DST) + w * 512);                                  \
        gload16(ab + 131072 + voffA, (DST) + 2048 + w * 512);                  \
    }

#define LOADB_HI(t_)                                                           \
    {                                                                          \
        const char* bhp = BH0 + (size_t)(t_) * 163840;                         \
        _Pragma("unroll")                                                      \
        for (int g = 0; g < 5; g++) bh[g] = *(const s16x8*)(bhp + vB[g]);      \
    }

#define LOADB_LO(t_)                                                           \
    {                                                                          \
        const char* blp = BL0 + (size_t)(t_) * 163840;                         \
        _Pragma("unroll")                                                      \
        for (int g = 0; g < 5; g++) bl[g] = *(const s16x8*)(blp + vB[g]);      \
    }

#define READ_AH(ABASE)                                                         \
    {                                                                          \
        _Pragma("unroll")                                                      \
        for (int rf = 0; rf < 4; rf++)                                         \
            ah[rf] = *(const s16x8*)&(ABASE)[aoh + rf * 1024];                 \
    }

#define READ_AL(ABASE)                                                         \
    {                                                                          \
        _Pragma("unroll")                                                      \
        for (int rf = 0; rf < 4; rf++)                                         \
            al[rf] = *(const s16x8*)&(ABASE)[aol + rf * 1024];                 \
    }

#define MFMA_PASS(AREGS, BSET)                                                 \
    {                                                                          \
        __builtin_amdgcn_s_setprio(1);                                         \
        _Pragma("unroll")                                                      \
        for (int rf = 0; rf < 4; rf++)                                         \
            _Pragma("unroll")                                                  \
            for (int g = 0; g < 5; g++)                                        \
                acc[rf][g] = __builtin_amdgcn_mfma_f32_16x16x32_bf16(AREGS[rf], BSET[g], acc[rf][g], 0, 0, 0); \
        __builtin_amdgcn_s_setprio(0);                                         \
    }

#define WINDOW(ACUR, ANXT, t0_, more_)                                         \
    {                                                                          \
        if (more_) {                                                           \
            STAGEA2(ANXT, (t0_) + 2);                                          \
            STAGEA2((ANXT) + 4096, (t0_) + 3);                                 \
            __builtin_amdgcn_sched_barrier(0);                                 \
        }                                                                      \
        MFMA_PASS(ah, bh);                                                     \
        MFMA_PASS(al, bh);                                                     \
        LOADB_HI((t0_) + 1);                                                   \
        READ_AL((ACUR) + 4096);                                                \
        MFMA_PASS(ah, bl);                                                     \
        LOADB_LO((t0_) + 1);                                                   \
        READ_AH((ACUR) + 4096);                                                \
        MFMA_PASS(al, bh);                                                     \
        MFMA_PASS(ah, bh);                                                     \
        if (more_) LOADB_HI((t0_) + 2);                                        \
        MFMA_PASS(ah, bl);                                                     \
        if (more_) LOADB_LO((t0_) + 2);                                        \
        if (more_) {                                                           \
            asm volatile("s_waitcnt vmcnt(10)" ::: "memory");                  \
            __builtin_amdgcn_s_barrier();                                      \
            __builtin_amdgcn_sched_barrier(0);                                 \
            READ_AH(ANXT);                                                     \
            READ_AL(ANXT);                                                     \
        }                                                                      \
    }

    STAGEA2(Ab0, 0);
    STAGEA2(Ab0 + 4096, 1);
    __builtin_amdgcn_sched_barrier(0);
    LOADB_HI(0);
    LOADB_LO(0);
    asm volatile("s_waitcnt vmcnt(10)" ::: "memory");
    __builtin_amdgcn_s_barrier();
    __builtin_amdgcn_sched_barrier(0);
    READ_AH(Ab0);
    READ_AL(Ab0);

#pragma unroll 1
    for (int t0 = 0; t0 < NITER; t0 += 4) {
        WINDOW(Ab0, Ab1, t0, 1);
        WINDOW(Ab1, Ab0, t0 + 2, (t0 + 4 < NITER));
    }
#undef STAGEA2
#undef LOADB_HI
#undef LOADB_LO
#undef READ_AH
#undef READ_AL
#undef MFMA_PASS
#undef WINDOW

    const int jglob = j0 + wc * 16 + il;
    const float bi  = b_iou[jglob];
    const float bo_ = b_iou[512 + jglob];
    const float bu  = b_iou[1024 + jglob];
    const float bfl = b_f[jglob];
    const float bfr = b_f[512 + jglob];

#pragma unroll
    for (int rf = 0; rf < 4; rf++) {
#pragma unroll
        for (int r = 0; r < 4; r++) {
            const int m  = m0 + rf * 16 + kq * 4 + r;
            const int b  = m >> lgnp;
            const int p  = m & (np - 1);
            float i_ = acc[rf][0][r] + bi;
            float o_ = acc[rf][1][r] + bo_;
            float u_ = acc[rf][2][r] + bu;
            float fl = sigm(acc[rf][3][r] + bfl);
            float fr = sigm(acc[rf][4][r] + bfr);
            float cl = 0.0f, cr_ = 0.0f;
            if (!LEAF) {
                size_t cb_ = ((size_t)b * nc + 2 * p) * 512 + jglob;
                cl  = Cc[cb_];
                cr_ = Cc[cb_ + 512];
            }
            float cn = sigm(i_) * tanhf(u_) + fl * cl + fr * cr_;
            float hn = sigm(o_) * tanhf(cn);
            size_t prow = (size_t)b * np + p;
            u16 hh  = f2bf(hn);
            u16 hlo = f2bf(hn - bf2f(hh));
            Hp[prow * 1024 + (size_t)(jg * 4 + wc) * 32 + il]      = hh;
            Hp[prow * 1024 + (size_t)(jg * 4 + wc) * 32 + 16 + il] = hlo;
            Cp[prow * 512 + jglob] = cn;
        }
    }
}

// ---------------- small levels (np<64): 32 j-groups x 16 j, waves split rows -------------
// 4x more blocks than before (grid 32 x np): per-block B slice 328 KB, all 4 waves share
// one B fragment (L1 dedup). Same window k-loop skeleton as level_big. A rows are globally
// contiguous across batches (child rows per batch exactly tile the H buffer), so
// A0u = Hc + m0*2048 u16 even when a block spans batches.
__global__ __launch_bounds__(256, 2)
void level_small2(const u16* __restrict__ Hc, const float* __restrict__ Cc,
                  const float* __restrict__ b_iou, const float* __restrict__ b_f,
                  u16* __restrict__ Hp, float* __restrict__ Cp,
                  int np, int lgnp)
{
    __shared__ __align__(16) u16 Ab0[8192];
    __shared__ __align__(16) u16 Ab1[8192];

    const int tid = threadIdx.x;
    const int jg  = blockIdx.x;          // 0..31, one 16-d chunk; XCD = jg % 8
    const int m0  = blockIdx.y * 64;
    const int j0  = jg * 16;
    const int nc  = np * 2;

    const int w    = tid >> 6;           // wave -> row quarter
    const int lane = tid & 63;
    const int il   = lane & 15;
    const int kq   = lane >> 4;

    f32x4 acc[5];
#pragma unroll
    for (int g = 0; g < 5; g++) acc[g] = (f32x4)0.0f;

    const char* A0u = (const char*)(Hc + (size_t)m0 * 2048);   // globally contiguous rows
    const int rowS = tid >> 3;
    const int segS = (tid & 7) ^ (rowS & 7);
    const unsigned voffA = (unsigned)rowS * 4096u + (unsigned)segS * 16u;

    const int shi = ((kq >> 1) << 2) | (kq & 1);
    const int x7  = il & 7;                          // (w*16+il)&7 == il&7
    const int aoh = (w * 16 + il) * 64 + ((shi ^ x7) * 8);
    const int aol = (w * 16 + il) * 64 + (((shi + 2) ^ x7) * 8);

    const char* BH0 = (const char*)(g_Bhi + (size_t)j0 * 32);
    const char* BL0 = (const char*)(g_Blo + (size_t)j0 * 32);
    unsigned vB[5];
#pragma unroll
    for (int g = 0; g < 5; g++)
        vB[g] = (unsigned)((il * 32 + kq * 8) * 2 + g * 32768);

    s16x8 bh[5], bl[5];
    s16x8 ah, al;

#define SSTAGEA2(DST, t_)                                                      \
    {                                                                          \
        const char* ab = A0u + (size_t)(t_) * 128;                             \
        gload16(ab + voffA, (DST) + w * 512);                                  \
        gload16(ab + 131072 + voffA, (DST) + 2048 + w * 512);                  \
    }

#define SLOADB_HI(t_)                                                          \
    {                                                                          \
        const char* bhp = BH0 + (size_t)(t_) * 163840;                         \
        _Pragma("unroll")                                                      \
        for (int g = 0; g < 5; g++) bh[g] = *(const s16x8*)(bhp + vB[g]);      \
    }

#define SLOADB_LO(t_)                                                          \
    {                                                                          \
        const char* blp = BL0 + (size_t)(t_) * 163840;                         \
        _Pragma("unroll")                                                      \
        for (int g = 0; g < 5; g++) bl[g] = *(const s16x8*)(blp + vB[g]);      \
    }

#define SREAD_AH(ABASE)  { ah = *(const s16x8*)&(ABASE)[aoh]; }
#define SREAD_AL(ABASE)  { al = *(const s16x8*)&(ABASE)[aol]; }

#define SMFMA_PASS(AREG, BSET)                                                 \
    {                                                                          \
        _Pragma("unroll")                                                      \
        for (int g = 0; g < 5; g++)                                            \
            acc[g] = __builtin_amdgcn_mfma_f32_16x16x32_bf16(AREG, BSET[g], acc[g], 0, 0, 0); \
    }

#define SWINDOW(ACUR, ANXT, t0_, more_)                                        \
    {                                                                          \
        if (more_) {                                                           \
            SSTAGEA2(ANXT, (t0_) + 2);                                         \
            SSTAGEA2((ANXT) + 4096, (t0_) + 3);                                \
            __builtin_amdgcn_sched_barrier(0);                                 \
        }                                                                      \
        SMFMA_PASS(ah, bh);                                                    \
        SMFMA_PASS(al, bh);                                                    \
        SLOADB_HI((t0_) + 1);                                                  \
        SREAD_AL((ACUR) + 4096);                                               \
        SMFMA_PASS(ah, bl);                                                    \
        SLOADB_LO((t0_) + 1);                                                  \
        SREAD_AH((ACUR) + 4096);                                               \
        SMFMA_PASS(al, bh);                                                    \
        SMFMA_PASS(ah, bh);                                                    \
        if (more_) SLOADB_HI((t0_) + 2);                                       \
        SMFMA_PASS(ah, bl);                                                    \
        if (more_) SLOADB_LO((t0_) + 2);                                       \
        if (more_) {                                                           \
            asm volatile("s_waitcnt vmcnt(10)" ::: "memory");                  \
            __builtin_amdgcn_s_barrier();                                      \
            __builtin_amdgcn_sched_barrier(0);                                 \
            SREAD_AH(ANXT);                                                    \
            SREAD_AL(ANXT);                                                    \
        }                                                                      \
    }

    SSTAGEA2(Ab0, 0);
    SSTAGEA2(Ab0 + 4096, 1);
    __builtin_amdgcn_sched_barrier(0);
    SLOADB_HI(0);
    SLOADB_LO(0);
    asm volatile("s_waitcnt vmcnt(10)" ::: "memory");
    __builtin_amdgcn_s_barrier();
    __builtin_amdgcn_sched_barrier(0);
    SREAD_AH(Ab0);
    SREAD_AL(Ab0);

#pragma unroll 1
    for (int t0 = 0; t0 < NITER; t0 += 4) {
        SWINDOW(Ab0, Ab1, t0, 1);
        SWINDOW(Ab1, Ab0, t0 + 2, (t0 + 4 < NITER));
    }
#undef SSTAGEA2
#undef SLOADB_HI
#undef SLOADB_LO
#undef SREAD_AH
#undef SREAD_AL
#undef SMFMA_PASS
#undef SWINDOW

    // ---- fused LSTM epilogue ----
    const int jglob = j0 + il;
    const float bi  = b_iou[jglob];
    const float bo_ = b_iou[512 + jglob];
    const float bu  = b_iou[1024 + jglob];
    const float bfl = b_f[jglob];
    const float bfr = b_f[512 + jglob];

#pragma unroll
    for (int r = 0; r < 4; r++) {
        const int m = m0 + w * 16 + kq * 4 + r;
        const int b = m >> lgnp;
        const int p = m & (np - 1);
        float i_ = acc[0][r] + bi;
        float o_ = acc[1][r] + bo_;
        float u_ = acc[2][r] + bu;
        float fl = sigm(acc[3][r] + bfl);
        float fr = sigm(acc[4][r] + bfr);
        size_t cb_ = ((size_t)b * nc + 2 * p) * 512 + jglob;
        float cl  = Cc[cb_];
        float cr_ = Cc[cb_ + 512];
        float cn = sigm(i_) * tanhf(u_) + fl * cl + fr * cr_;
        float hn = sigm(o_) * tanhf(cn);
        size_t prow = (size_t)b * np + p;
        u16 hh  = f2bf(hn);
        u16 hlo = f2bf(hn - bf2f(hh));
        Hp[prow * 1024 + (size_t)jg * 32 + il]      = hh;
        Hp[prow * 1024 + (size_t)jg * 32 + 16 + il] = hlo;
        Cp[prow * 512 + jglob] = cn;
    }
}

// ---------------- out[b][c] = sum_d h_root[b][d] * W_out[d][c] ----------------
__global__ __launch_bounds__(256)
void out_kernel(const u16* __restrict__ Hroot, const float* __restrict__ W_out,
                float* __restrict__ out)
{
    const int b = blockIdx.x;
    const int tid = threadIdx.x;
    float s0 = 0.f, s1 = 0.f;
    for (int d = tid; d < 512; d += 256) {
        const u16* row = Hroot + (size_t)b * 1024 + (d >> 4) * 32 + (d & 15);
        float h = bf2f(row[0]) + bf2f(row[16]);
        s0 = fmaf(h, W_out[d * 2 + 0], s0);
        s1 = fmaf(h, W_out[d * 2 + 1], s1);
    }
#pragma unroll
    for (int off = 32; off > 0; off >>= 1) {
        s0 += __shfl_down(s0, off, 64);
        s1 += __shfl_down(s1, off, 64);
    }
    __shared__ float red[2][4];
    const int wave = tid >> 6;
    if ((tid & 63) == 0) { red[0][wave] = s0; red[1][wave] = s1; }
    __syncthreads();
    if (tid == 0) {
        float t0 = 0.f, t1 = 0.f;
#pragma unroll
        for (int wv = 0; wv < 4; wv++) { t0 += red[0][wv]; t1 += red[1][wv]; }
        out[b * 2 + 0] = t0;
        out[b * 2 + 1] = t1;
    }
}

extern "C" void kernel_launch(void* const* d_in, const int* in_sizes, int n_in,
                              void* d_out, int out_size, void* d_ws, size_t ws_size,
                              hipStream_t stream)
{
    const int*   tokens = (const int*)  d_in[0];
    const float* emb    = (const float*)d_in[1];
    const float* W_iou  = (const float*)d_in[2];
    const float* b_iou  = (const float*)d_in[3];
    const float* W_f    = (const float*)d_in[4];
    const float* b_f    = (const float*)d_in[5];
    const float* W_out  = (const float*)d_in[6];
    float* out = (float*)d_out;

    // ws layout (201.3 MB, proven):
    u16*   H0 = (u16*)d_ws;
    float* C0 = (float*)(H0 + (size_t)512 * 64 * 1024);
    u16*   H1 = (u16*)(C0 + (size_t)512 * 64 * 512);
    float* C1 = (float*)(H1 + (size_t)256 * 64 * 1024);

    wsplit_kernel<<<dim3(32, 40), 256, 0, stream>>>(W_iou, W_f);
    leafgather_kernel<<<8192, 256, 0, stream>>>(tokens, emb);

    // level 9: leaves -> 512 parents (A = g_Aleaf, c = 0)
    level_big<true><<<dim3(8, 512), 256, 0, stream>>>(
        nullptr, nullptr, b_iou, b_f, H0, C0, 512, 9);

    u16* Hc = H0;  float* Cc = C0;
    u16* Hp = H1;  float* Cp = C1;
    for (int L = 8; L >= 0; L--) {
        const int np = 1 << L;
        if (np >= 64) {
            level_big<false><<<dim3(8, np), 256, 0, stream>>>(
                Hc, Cc, b_iou, b_f, Hp, Cp, np, L);
        } else {
            level_small2<<<dim3(32, np), 256, 0, stream>>>(
                Hc, Cc, b_iou, b_f, Hp, Cp, np, L);
        }
        u16* tH = Hc; Hc = Hp; Hp = tH;
        float* tC = Cc; Cc = Cp; Cp = tC;
    }

    out_kernel<<<64, 256, 0, stream>>>(Hc, W_out, out);
}